// Round 9
// baseline (133.293 us; speedup 1.0000x reference)
//
#include <hip/hip_runtime.h>
#include <stdint.h>

#define B 4
#define S 2048
#define E 2048
#define H 128

typedef _Float16 f16;
typedef _Float16 half4 __attribute__((ext_vector_type(4)));
typedef _Float16 half8 __attribute__((ext_vector_type(8)));
typedef float f32x4 __attribute__((ext_vector_type(4)));

// MFMA 16x16x32 f16 (m89/m91):
//   A-frag: lane(quad,lx) holds A[m=lx][k=quad*8+j]
//   B-frag: lane(quad,lx) holds B[k=quad*8+j][n=lx]
//   C/D  : lane(quad,lx) holds D[row=quad*4+reg][col=lx]
// FRAG-LINEAR GLOBAL: frag f = 512 f16 at dst[f*512 + lane*8 .. +8].

// Raw barrier: lgkm-only wait + s_barrier (no vmcnt drain).
#define BAR() do { asm volatile("s_waitcnt lgkmcnt(0)" ::: "memory"); \
    __builtin_amdgcn_s_barrier(); \
    asm volatile("" ::: "memory"); } while (0)

// ---------------------------------------------------------------------------
// Kernel 0: W matrices fp32 [128][2048] -> frag-linear f16. (original)
//   WQ -> Wf frag = kc*16 + rt ; WK -> +8 ; WV -> Vf frag = kc*8 + rt
// ---------------------------------------------------------------------------
__global__ __launch_bounds__(256) void cvt_w_kernel(
    const float* __restrict__ WQ, const float* __restrict__ WK,
    const float* __restrict__ WV,
    f16* __restrict__ Wf, f16* __restrict__ Vf)
{
    __shared__ __align__(16) f16 LT[4 * 512];
    const int t   = threadIdx.x;
    const int cc  = blockIdx.x;
    const int rt  = blockIdx.y;
    const int mat = blockIdx.z;
    const float* src = (mat == 0) ? WQ : (mat == 1) ? WK : WV;

#pragma unroll
    for (int i = 0; i < 2; ++i) {
        const int idx = i * 256 + t;
        const int row = idx >> 5;
        const int c4  = idx & 31;
        float4 v = ((const float4*)src)[(size_t)(rt * 16 + row) * (E / 4) + cc * 32 + c4];
        const int e0   = c4 * 4;
        const int kcl  = e0 >> 5;
        const int quad = (e0 >> 3) & 3;
        const int j    = e0 & 7;
        half4 hv;
        hv[0] = (f16)v.x; hv[1] = (f16)v.y; hv[2] = (f16)v.z; hv[3] = (f16)v.w;
        *(half4*)&LT[(kcl * 64 + quad * 16 + row) * 8 + j] = hv;
    }
    __syncthreads();

    const half8 val = *(const half8*)&LT[t * 8];
    const int kcg = cc * 4 + (t >> 6);
    const int ln  = t & 63;
    if (mat == 2) *(half8*)&Vf[((size_t)kcg * 8  + rt)           * 512 + ln * 8] = val;
    else          *(half8*)&Wf[((size_t)kcg * 16 + rt + mat * 8) * 512 + ln * 8] = val;
}

// ---------------------------------------------------------------------------
// Kernel 1 (v7): Q,K projection at 8 waves/SIMD.
// 512 blocks x 1024 thr, 16 rows/block, full-K X in 64 KB LDS ->
// 2 blocks/CU co-resident (lb(1024,8) caps VGPR at 64; k-loop live ~30).
// Mechanism vs v2/v6 (both neutral): k-loop is L2-LATENCY-bound at 4
// waves/SIMD; doubling resident waves doubles coverage, and the co-resident
// block overlaps its HBM staging with this block's L2 k-loop.
// Wf walk: rot = (blockIdx>>1)&63 -> co-resident pair walks the SAME kc
// sequence under either pairing ((2i,2i+1) trivially; (i,i+256): 128&63=0)
// -> pair's B-frag reads share L1/L2-hot lines, neutralizing the 2x
// block-count Wf traffic.
// Staging: R1's coalesced pattern (wave = 2 KB contiguous) + bank swizzle.
// ---------------------------------------------------------------------------
__global__ __launch_bounds__(1024, 8) void proj_kernel(
    const float4* __restrict__ X,      // [B*S][E/4] fp32
    const f16* __restrict__ Wf,
    f16* __restrict__ Qf, f16* __restrict__ Kf)
{
    __shared__ __align__(16) f16 XA[4096 * 8];   // 64 KB; slot = 16B unit
    const int t    = threadIdx.x;
    const int w    = t >> 6;
    const int lane = t & 63;
    const int quad = lane >> 4;
    const int lx   = lane & 15;
    const int r0   = blockIdx.x * 16;

    // ---- stage X: 16 rows x 2048 k, fp32 -> f16 frag-linear, coalesced ----
    // pair p = row*256 + c42: thread loads 2 consecutive float4 (one j-run).
    float4 xv[8];
#pragma unroll
    for (int i = 0; i < 4; ++i) {
        const int p   = i * 1024 + t;
        const int row = p >> 8;
        const int c42 = p & 255;
        const float4* xp = &X[(size_t)(r0 + row) * (E / 4) + c42 * 2];
        xv[i * 2]     = xp[0];
        xv[i * 2 + 1] = xp[1];
    }
#pragma unroll
    for (int i = 0; i < 4; ++i) {
        const int p   = i * 1024 + t;
        const int row = p >> 8;                   // m, 0..15
        const int c42 = p & 255;
        const int kc  = c42 >> 2;
        const int qs  = c42 & 3;
        const int mp  = row ^ ((qs << 1) | (kc & 1));    // bank swizzle
        half8 hv;
        hv[0] = (f16)xv[i * 2].x;     hv[1] = (f16)xv[i * 2].y;
        hv[2] = (f16)xv[i * 2].z;     hv[3] = (f16)xv[i * 2].w;
        hv[4] = (f16)xv[i * 2 + 1].x; hv[5] = (f16)xv[i * 2 + 1].y;
        hv[6] = (f16)xv[i * 2 + 1].z; hv[7] = (f16)xv[i * 2 + 1].w;
        *(half8*)&XA[(size_t)(kc * 64 + qs * 16 + mp) * 8] = hv;
    }
    __syncthreads();

    // ---- barrier-free K-loop: 64 x (1 ds_read + 1 global b128 + 1 MFMA) ----
    f32x4 C = f32x4{0.f, 0.f, 0.f, 0.f};
    const f16* wbase = &Wf[(size_t)w * 512 + lane * 8];     // frag kc*16 + w
    const int rot = (blockIdx.x >> 1) & 63;     // pair-aligned Wf walk
#pragma unroll 8
    for (int kk = 0; kk < 64; ++kk) {
        const int kc  = (kk + rot) & 63;
        const int lxs = lx ^ ((quad << 1) | (kc & 1));
        half8 b = *(const half8*)&wbase[(size_t)kc * 16 * 512];          // L2
        half8 a = *(const half8*)&XA[(size_t)(kc * 64 + quad * 16 + lxs) * 8];
        C = __builtin_amdgcn_mfma_f32_16x16x32_f16(a, b, C, 0, 0, 0);
    }

    // ---- epilogue: C -> LT (target frag layout, reuse XA) -> global ----
    __syncthreads();                      // all XA reads done; alias as LT
    f16* LT = XA;                         // 8 frags = 8 KB
    {
        const int qt2 = (w & 1) * 2 + (lx >> 3);
        const int jt  = lx & 7;
#pragma unroll
        for (int reg = 0; reg < 4; ++reg)
            LT[(((w >> 1) * 64) + qt2 * 16 + quad * 4 + reg) * 8 + jt] = (f16)C[reg];
    }
    __syncthreads();
    if (t < 512) {
        const half8 v = *(const half8*)&LT[t * 8];
        const int f = t >> 6, ln = t & 63;
        f16* dst = (f < 4) ? Qf : Kf;
        *(half8*)&dst[((size_t)blockIdx.x * 4 + (f & 3)) * 512 + ln * 8] = v;
    }
}

// ---------------------------------------------------------------------------
// Kernel 2 (v4, best-known from R6): attention, R4 CU-balanced map.
// ---------------------------------------------------------------------------
__global__ __launch_bounds__(512, 4) void attn_kernel(
    const f16* __restrict__ Qf, const f16* __restrict__ Kf,
    const f16* __restrict__ Vf,
    float* __restrict__ out)
{
    __shared__ __align__(16) f16 PL[2 * 4 * 512];   // 8 KB, parity-buffered
    __shared__ float lred[8][16];

    const int t    = threadIdx.x;
    const int w    = t >> 6;
    const int lane = t & 63;
    const int quad = lane >> 4;
    const int lx   = lane & 15;

    const int j    = blockIdx.x & 255;
    const int r    = blockIdx.x >> 8;
    const int u    = j & 127;
    const int q0t  = (u & 1) ? (127 - (u >> 1)) : (u >> 1);
    const int qt   = r ? (127 - q0t) : q0t;
    const int b    = (j >> 7) + (r << 1);
    const int q0   = qt * 16;
    const int tb   = b * 128;

    half8 qa0, qa1, qa2, qa3;
    {
        const f16* qp = &Qf[(((size_t)(tb + qt)) * 4) * 512 + lane * 8];
        qa0 = *(const half8*)&qp[0];    qa1 = *(const half8*)&qp[512];
        qa2 = *(const half8*)&qp[1024]; qa3 = *(const half8*)&qp[1536];
    }

    f32x4 O = f32x4{0.f, 0.f, 0.f, 0.f};
    float lp0 = 0.f, lp1 = 0.f, lp2 = 0.f, lp3 = 0.f;

    const int nch = (qt >> 3) + 1;

    half8 kbA0, kbA1, kbA2, kbA3, vbA0, vbA1, vbA2, vbA3;
    half8 kbB0, kbB1, kbB2, kbB3, vbB0, vbB1, vbB2, vbB3;

#define LOADKV(c, K0, K1, K2, K3, V0, V1, V2, V3)                              \
    {                                                                          \
        const f16* kp_ = &Kf[(((size_t)(tb + (c) * 8 + w)) * 4) * 512 + lane * 8]; \
        K0 = *(const half8*)&kp_[0];    K1 = *(const half8*)&kp_[512];         \
        K2 = *(const half8*)&kp_[1024]; K3 = *(const half8*)&kp_[1536];        \
        const f16* vp_ = &Vf[(((size_t)(c) * 4 * 8) + w) * 512 + lane * 8];    \
        V0 = *(const half8*)&vp_[0];     V1 = *(const half8*)&vp_[4096];       \
        V2 = *(const half8*)&vp_[8192];  V3 = *(const half8*)&vp_[12288];      \
    }

#define STEP(c, K0, K1, K2, K3, V0, V1, V2, V3, NK0, NK1, NK2, NK3, NV0, NV1, NV2, NV3) \
    {                                                                          \
        if ((c) + 1 < nch) LOADKV((c) + 1, NK0, NK1, NK2, NK3, NV0, NV1, NV2, NV3) \
        f32x4 Sc = f32x4{0.f, 0.f, 0.f, 0.f};                                  \
        __builtin_amdgcn_s_setprio(1);                                         \
        Sc = __builtin_amdgcn_mfma_f32_16x16x32_f16(qa0, K0, Sc, 0, 0, 0);     \
        Sc = __builtin_amdgcn_mfma_f32_16x16x32_f16(qa1, K1, Sc, 0, 0, 0);     \
        Sc = __builtin_amdgcn_mfma_f32_16x16x32_f16(qa2, K2, Sc, 0, 0, 0);     \
        Sc = __builtin_amdgcn_mfma_f32_16x16x32_f16(qa3, K3, Sc, 0, 0, 0);     \
        __builtin_amdgcn_s_setprio(0);                                         \
        const int sgc_ = (c) * 128 + w * 16 + lx;                              \
        const int qp2_ = (w & 1) * 2 + (lx >> 3);                              \
        f16* plw_ = &PL[((c) & 1) * 2048 + (w >> 1) * 512];                    \
        _Pragma("unroll")                                                      \
        for (int reg = 0; reg < 4; ++reg) {                                    \
            const int q_ = quad * 4 + reg;                                     \
            float p_ = (sgc_ <= q0 + q_)                                       \
                       ? __expf(Sc[reg] * 0.08838834764831845f - 10.0f)        \
                       : 0.f;                                                  \
            if (reg == 0) lp0 += p_; else if (reg == 1) lp1 += p_;             \
            else if (reg == 2) lp2 += p_; else lp3 += p_;                      \
            plw_[(qp2_ * 16 + q_) * 8 + (lx & 7)] = (f16)p_;                   \
        }                                                                      \
        BAR();                                                                 \
        const f16* plr_ = &PL[((c) & 1) * 2048];                               \
        const half8 pa0_ = *(const half8*)&plr_[lane * 8];                     \
        const half8 pa1_ = *(const half8*)&plr_[512 + lane * 8];               \
        const half8 pa2_ = *(const half8*)&plr_[1024 + lane * 8];              \
        const half8 pa3_ = *(const half8*)&plr_[1536 + lane * 8];              \
        __builtin_amdgcn_s_setprio(1);                                         \
        O = __builtin_amdgcn_mfma_f32_16x16x32_f16(pa0_, V0, O, 0, 0, 0);      \
        O = __builtin_amdgcn_mfma_f32_16x16x32_f16(pa1_, V1, O, 0, 0, 0);      \
        O = __builtin_amdgcn_mfma_f32_16x16x32_f16(pa2_, V2, O, 0, 0, 0);      \
        O = __builtin_amdgcn_mfma_f32_16x16x32_f16(pa3_, V3, O, 0, 0, 0);      \
        __builtin_amdgcn_s_setprio(0);                                         \
    }

    LOADKV(0, kbA0, kbA1, kbA2, kbA3, vbA0, vbA1, vbA2, vbA3)
    int c = 0;
    while (true) {
        STEP(c, kbA0, kbA1, kbA2, kbA3, vbA0, vbA1, vbA2, vbA3,
                kbB0, kbB1, kbB2, kbB3, vbB0, vbB1, vbB2, vbB3)
        ++c; if (c >= nch) break;
        STEP(c, kbB0, kbB1, kbB2, kbB3, vbB0, vbB1, vbB2, vbB3,
                kbA0, kbA1, kbA2, kbA3, vbA0, vbA1, vbA2, vbA3)
        ++c; if (c >= nch) break;
    }
#undef STEP
#undef LOADKV

    {
        float v0 = lp0, v1 = lp1, v2 = lp2, v3 = lp3;
        v0 += __shfl_xor(v0, 1, 64); v0 += __shfl_xor(v0, 2, 64);
        v0 += __shfl_xor(v0, 4, 64); v0 += __shfl_xor(v0, 8, 64);
        v1 += __shfl_xor(v1, 1, 64); v1 += __shfl_xor(v1, 2, 64);
        v1 += __shfl_xor(v1, 4, 64); v1 += __shfl_xor(v1, 8, 64);
        v2 += __shfl_xor(v2, 1, 64); v2 += __shfl_xor(v2, 2, 64);
        v2 += __shfl_xor(v2, 4, 64); v2 += __shfl_xor(v2, 8, 64);
        v3 += __shfl_xor(v3, 1, 64); v3 += __shfl_xor(v3, 2, 64);
        v3 += __shfl_xor(v3, 4, 64); v3 += __shfl_xor(v3, 8, 64);
        if (lx == 0) {
            lred[w][quad * 4 + 0] = v0;
            lred[w][quad * 4 + 1] = v1;
            lred[w][quad * 4 + 2] = v2;
            lred[w][quad * 4 + 3] = v3;
        }
    }
    __syncthreads();
#pragma unroll
    for (int reg = 0; reg < 4; ++reg) {
        const int q = quad * 4 + reg;
        float lsum = 0.f;
#pragma unroll
        for (int ww = 0; ww < 8; ++ww) lsum += lred[ww][q];
        out[((size_t)(tb + qt) * 16 + q) * 128 + w * 16 + lx] = O[reg] / lsum;
    }
}

extern "C" void kernel_launch(void* const* d_in, const int* in_sizes, int n_in,
                              void* d_out, int out_size, void* d_ws, size_t ws_size,
                              hipStream_t stream) {
    const float4* X  = (const float4*)d_in[0];
    const float*  WQ = (const float*)d_in[1];
    const float*  WK = (const float*)d_in[2];
    const float*  WV = (const float*)d_in[3];

    f16* Wf = (f16*)d_ws;                     // 1024 frags  1 MB
    f16* Vf = Wf + (size_t)1024 * 512;        //  512 frags  0.5 MB
    f16* Qf = Vf + (size_t)512 * 512;         // 2048 frags  2 MB
    f16* Kf = Qf + (size_t)2048 * 512;        // 2048 frags  2 MB

    cvt_w_kernel<<<dim3(16, 8, 3), 256, 0, stream>>>(WQ, WK, WV, Wf, Vf);
    proj_kernel<<<512, 1024, 0, stream>>>(X, Wf, Qf, Kf);
    attn_kernel<<<512, 512, 0, stream>>>(Qf, Kf, Vf, (float*)d_out);
}

// Round 10
// 131.735 us; speedup vs baseline: 1.0118x; 1.0118x over previous
//
#include <hip/hip_runtime.h>
#include <stdint.h>

#define B 4
#define S 2048
#define E 2048
#define H 128

typedef _Float16 f16;
typedef _Float16 half4 __attribute__((ext_vector_type(4)));
typedef _Float16 half8 __attribute__((ext_vector_type(8)));
typedef float f32x4 __attribute__((ext_vector_type(4)));

// MFMA 16x16x32 f16 (m89/m91):
//   A-frag: lane(quad,lx) holds A[m=lx][k=quad*8+j]
//   B-frag: lane(quad,lx) holds B[k=quad*8+j][n=lx]
//   C/D  : lane(quad,lx) holds D[row=quad*4+reg][col=lx]
// FRAG-LINEAR GLOBAL: frag f = 512 f16 at dst[f*512 + lane*8 .. +8].

// Raw barrier: lgkm-only wait + s_barrier (no vmcnt drain).
#define BAR() do { asm volatile("s_waitcnt lgkmcnt(0)" ::: "memory"); \
    __builtin_amdgcn_s_barrier(); \
    asm volatile("" ::: "memory"); } while (0)

// ---------------------------------------------------------------------------
// Kernel 0: W matrices fp32 [128][2048] -> frag-linear f16. (original)
// ---------------------------------------------------------------------------
__global__ __launch_bounds__(256) void cvt_w_kernel(
    const float* __restrict__ WQ, const float* __restrict__ WK,
    const float* __restrict__ WV,
    f16* __restrict__ Wf, f16* __restrict__ Vf)
{
    __shared__ __align__(16) f16 LT[4 * 512];
    const int t   = threadIdx.x;
    const int cc  = blockIdx.x;
    const int rt  = blockIdx.y;
    const int mat = blockIdx.z;
    const float* src = (mat == 0) ? WQ : (mat == 1) ? WK : WV;

#pragma unroll
    for (int i = 0; i < 2; ++i) {
        const int idx = i * 256 + t;
        const int row = idx >> 5;
        const int c4  = idx & 31;
        float4 v = ((const float4*)src)[(size_t)(rt * 16 + row) * (E / 4) + cc * 32 + c4];
        const int e0   = c4 * 4;
        const int kcl  = e0 >> 5;
        const int quad = (e0 >> 3) & 3;
        const int j    = e0 & 7;
        half4 hv;
        hv[0] = (f16)v.x; hv[1] = (f16)v.y; hv[2] = (f16)v.z; hv[3] = (f16)v.w;
        *(half4*)&LT[(kcl * 64 + quad * 16 + row) * 8 + j] = hv;
    }
    __syncthreads();

    const half8 val = *(const half8*)&LT[t * 8];
    const int kcg = cc * 4 + (t >> 6);
    const int ln  = t & 63;
    if (mat == 2) *(half8*)&Vf[((size_t)kcg * 8  + rt)           * 512 + ln * 8] = val;
    else          *(half8*)&Wf[((size_t)kcg * 16 + rt + mat * 8) * 512 + ln * 8] = val;
}

// ---------------------------------------------------------------------------
// Kernel 1 (v2, known-good from R1/R4): Q,K projection. 256 blocks x 1024
// thr, 32 rows/block, full-K X staged in 128 KB LDS (1 block/CU).
// Coalesced staging + bank swizzle; barrier-free 64-iter K-loop.
// ---------------------------------------------------------------------------
__global__ __launch_bounds__(1024, 4) void proj_kernel(
    const float4* __restrict__ X,      // [B*S][E/4] fp32
    const f16* __restrict__ Wf,
    f16* __restrict__ Qf, f16* __restrict__ Kf)
{
    __shared__ __align__(16) f16 XA[8192 * 8];   // 128 KB; slot = 16B unit
    const int t    = threadIdx.x;
    const int w    = t >> 6;
    const int lane = t & 63;
    const int quad = lane >> 4;
    const int lx   = lane & 15;
    const int r0   = blockIdx.x * 32;

    float4 xv[16];
#pragma unroll
    for (int i = 0; i < 8; ++i) {
        const int p   = i * 1024 + t;
        const int row = p >> 8;
        const int c42 = p & 255;
        const float4* xp = &X[(size_t)(r0 + row) * (E / 4) + c42 * 2];
        xv[i * 2]     = xp[0];
        xv[i * 2 + 1] = xp[1];
    }
#pragma unroll
    for (int i = 0; i < 8; ++i) {
        const int p   = i * 1024 + t;
        const int row = p >> 8;
        const int c42 = p & 255;
        const int kc  = c42 >> 2;
        const int qs  = c42 & 3;
        const int rt  = row >> 4;
        const int m   = row & 15;
        const int mp  = m ^ ((qs << 1) | (kc & 1));      // bank swizzle
        half8 hv;
        hv[0] = (f16)xv[i * 2].x;     hv[1] = (f16)xv[i * 2].y;
        hv[2] = (f16)xv[i * 2].z;     hv[3] = (f16)xv[i * 2].w;
        hv[4] = (f16)xv[i * 2 + 1].x; hv[5] = (f16)xv[i * 2 + 1].y;
        hv[6] = (f16)xv[i * 2 + 1].z; hv[7] = (f16)xv[i * 2 + 1].w;
        *(half8*)&XA[(size_t)(kc * 128 + rt * 64 + qs * 16 + mp) * 8] = hv;
    }
    __syncthreads();

    f32x4 C0 = f32x4{0.f, 0.f, 0.f, 0.f};
    f32x4 C1 = f32x4{0.f, 0.f, 0.f, 0.f};
    const f16* wbase = &Wf[(size_t)w * 512 + lane * 8];     // frag kc*16 + w
    const int rot = blockIdx.x & 63;
#pragma unroll 8
    for (int kk = 0; kk < 64; ++kk) {
        const int kc  = (kk + rot) & 63;
        const int lxs = lx ^ ((quad << 1) | (kc & 1));
        half8 b  = *(const half8*)&wbase[(size_t)kc * 16 * 512];          // L2
        half8 a0 = *(const half8*)&XA[(size_t)(kc * 128      + quad * 16 + lxs) * 8];
        half8 a1 = *(const half8*)&XA[(size_t)(kc * 128 + 64 + quad * 16 + lxs) * 8];
        C0 = __builtin_amdgcn_mfma_f32_16x16x32_f16(a0, b, C0, 0, 0, 0);
        C1 = __builtin_amdgcn_mfma_f32_16x16x32_f16(a1, b, C1, 0, 0, 0);
    }

    __syncthreads();                      // all XA reads done; alias as LT
    f16* LT = XA;                         // 16 frags = 16 KB
    {
        const int qt2 = (w & 1) * 2 + (lx >> 3);
        const int jt  = lx & 7;
        const int fl  = w >> 1;           // 0..7: (mat,hc)
#pragma unroll
        for (int reg = 0; reg < 4; ++reg) {
            LT[(size_t)((fl      * 64) + qt2 * 16 + quad * 4 + reg) * 8 + jt] = (f16)C0[reg];
            LT[(size_t)(((fl + 8) * 64) + qt2 * 16 + quad * 4 + reg) * 8 + jt] = (f16)C1[reg];
        }
    }
    __syncthreads();
    {
        const int f  = t >> 6;            // 0..15
        const int ln = t & 63;
        const half8 v = *(const half8*)&LT[(size_t)f * 512 + ln * 8];
        const int rt  = f >> 3;
        const int hc  = f & 3;
        const int mat = (f >> 2) & 1;
        f16* dst = mat ? Kf : Qf;
        *(half8*)&dst[((size_t)(blockIdx.x * 2 + rt) * 4 + hc) * 512 + ln * 8] = v;
    }
}

// ---------------------------------------------------------------------------
// Kernel 2 (v6): attention = v4 body, ONE change: __launch_bounds__(512, 2).
// R9 profile showed v4 at lb(512,4): VGPR_Count=64 (live set ~100+ -> ~40
// VGPR spilled to scratch), Occupancy 1.16%, all pipes <1.5% over 123 us:
// scratch-limited workgroup-launch THROTTLE. This explains the R5-R8
// structure-invariance: v1/v3/v4 all spilled -> all throttled identically.
// lb(512,2) caps VGPR at 256; compiler allocates the ~110-130 actually
// needed, zero scratch; at <=128 VGPR the HW still co-schedules 2 blocks/CU
// (resource-based), so occupancy is preserved and the throttle is gone.
// ---------------------------------------------------------------------------
__global__ __launch_bounds__(512, 2) void attn_kernel(
    const f16* __restrict__ Qf, const f16* __restrict__ Kf,
    const f16* __restrict__ Vf,
    float* __restrict__ out)
{
    __shared__ __align__(16) f16 PL[2 * 4 * 512];   // 8 KB, parity-buffered
    __shared__ float lred[8][16];

    const int t    = threadIdx.x;
    const int w    = t >> 6;
    const int lane = t & 63;
    const int quad = lane >> 4;
    const int lx   = lane & 15;

    const int j    = blockIdx.x & 255;
    const int r    = blockIdx.x >> 8;
    const int u    = j & 127;
    const int q0t  = (u & 1) ? (127 - (u >> 1)) : (u >> 1);
    const int qt   = r ? (127 - q0t) : q0t;
    const int b    = (j >> 7) + (r << 1);
    const int q0   = qt * 16;
    const int tb   = b * 128;

    half8 qa0, qa1, qa2, qa3;
    {
        const f16* qp = &Qf[(((size_t)(tb + qt)) * 4) * 512 + lane * 8];
        qa0 = *(const half8*)&qp[0];    qa1 = *(const half8*)&qp[512];
        qa2 = *(const half8*)&qp[1024]; qa3 = *(const half8*)&qp[1536];
    }

    f32x4 O = f32x4{0.f, 0.f, 0.f, 0.f};
    float lp0 = 0.f, lp1 = 0.f, lp2 = 0.f, lp3 = 0.f;

    const int nch = (qt >> 3) + 1;

    half8 kbA0, kbA1, kbA2, kbA3, vbA0, vbA1, vbA2, vbA3;
    half8 kbB0, kbB1, kbB2, kbB3, vbB0, vbB1, vbB2, vbB3;

#define LOADKV(c, K0, K1, K2, K3, V0, V1, V2, V3)                              \
    {                                                                          \
        const f16* kp_ = &Kf[(((size_t)(tb + (c) * 8 + w)) * 4) * 512 + lane * 8]; \
        K0 = *(const half8*)&kp_[0];    K1 = *(const half8*)&kp_[512];         \
        K2 = *(const half8*)&kp_[1024]; K3 = *(const half8*)&kp_[1536];        \
        const f16* vp_ = &Vf[(((size_t)(c) * 4 * 8) + w) * 512 + lane * 8];    \
        V0 = *(const half8*)&vp_[0];     V1 = *(const half8*)&vp_[4096];       \
        V2 = *(const half8*)&vp_[8192];  V3 = *(const half8*)&vp_[12288];      \
    }

#define STEP(c, K0, K1, K2, K3, V0, V1, V2, V3, NK0, NK1, NK2, NK3, NV0, NV1, NV2, NV3) \
    {                                                                          \
        if ((c) + 1 < nch) LOADKV((c) + 1, NK0, NK1, NK2, NK3, NV0, NV1, NV2, NV3) \
        f32x4 Sc = f32x4{0.f, 0.f, 0.f, 0.f};                                  \
        __builtin_amdgcn_s_setprio(1);                                         \
        Sc = __builtin_amdgcn_mfma_f32_16x16x32_f16(qa0, K0, Sc, 0, 0, 0);     \
        Sc = __builtin_amdgcn_mfma_f32_16x16x32_f16(qa1, K1, Sc, 0, 0, 0);     \
        Sc = __builtin_amdgcn_mfma_f32_16x16x32_f16(qa2, K2, Sc, 0, 0, 0);     \
        Sc = __builtin_amdgcn_mfma_f32_16x16x32_f16(qa3, K3, Sc, 0, 0, 0);     \
        __builtin_amdgcn_s_setprio(0);                                         \
        const int sgc_ = (c) * 128 + w * 16 + lx;                              \
        const int qp2_ = (w & 1) * 2 + (lx >> 3);                              \
        f16* plw_ = &PL[((c) & 1) * 2048 + (w >> 1) * 512];                    \
        _Pragma("unroll")                                                      \
        for (int reg = 0; reg < 4; ++reg) {                                    \
            const int q_ = quad * 4 + reg;                                     \
            float p_ = (sgc_ <= q0 + q_)                                       \
                       ? __expf(Sc[reg] * 0.08838834764831845f - 10.0f)        \
                       : 0.f;                                                  \
            if (reg == 0) lp0 += p_; else if (reg == 1) lp1 += p_;             \
            else if (reg == 2) lp2 += p_; else lp3 += p_;                      \
            plw_[(qp2_ * 16 + q_) * 8 + (lx & 7)] = (f16)p_;                   \
        }                                                                      \
        BAR();                                                                 \
        const f16* plr_ = &PL[((c) & 1) * 2048];                               \
        const half8 pa0_ = *(const half8*)&plr_[lane * 8];                     \
        const half8 pa1_ = *(const half8*)&plr_[512 + lane * 8];               \
        const half8 pa2_ = *(const half8*)&plr_[1024 + lane * 8];              \
        const half8 pa3_ = *(const half8*)&plr_[1536 + lane * 8];              \
        __builtin_amdgcn_s_setprio(1);                                         \
        O = __builtin_amdgcn_mfma_f32_16x16x32_f16(pa0_, V0, O, 0, 0, 0);      \
        O = __builtin_amdgcn_mfma_f32_16x16x32_f16(pa1_, V1, O, 0, 0, 0);      \
        O = __builtin_amdgcn_mfma_f32_16x16x32_f16(pa2_, V2, O, 0, 0, 0);      \
        O = __builtin_amdgcn_mfma_f32_16x16x32_f16(pa3_, V3, O, 0, 0, 0);      \
        __builtin_amdgcn_s_setprio(0);                                         \
    }

    LOADKV(0, kbA0, kbA1, kbA2, kbA3, vbA0, vbA1, vbA2, vbA3)
    int c = 0;
    while (true) {
        STEP(c, kbA0, kbA1, kbA2, kbA3, vbA0, vbA1, vbA2, vbA3,
                kbB0, kbB1, kbB2, kbB3, vbB0, vbB1, vbB2, vbB3)
        ++c; if (c >= nch) break;
        STEP(c, kbB0, kbB1, kbB2, kbB3, vbB0, vbB1, vbB2, vbB3,
                kbA0, kbA1, kbA2, kbA3, vbA0, vbA1, vbA2, vbA3)
        ++c; if (c >= nch) break;
    }
#undef STEP
#undef LOADKV

    {
        float v0 = lp0, v1 = lp1, v2 = lp2, v3 = lp3;
        v0 += __shfl_xor(v0, 1, 64); v0 += __shfl_xor(v0, 2, 64);
        v0 += __shfl_xor(v0, 4, 64); v0 += __shfl_xor(v0, 8, 64);
        v1 += __shfl_xor(v1, 1, 64); v1 += __shfl_xor(v1, 2, 64);
        v1 += __shfl_xor(v1, 4, 64); v1 += __shfl_xor(v1, 8, 64);
        v2 += __shfl_xor(v2, 1, 64); v2 += __shfl_xor(v2, 2, 64);
        v2 += __shfl_xor(v2, 4, 64); v2 += __shfl_xor(v2, 8, 64);
        v3 += __shfl_xor(v3, 1, 64); v3 += __shfl_xor(v3, 2, 64);
        v3 += __shfl_xor(v3, 4, 64); v3 += __shfl_xor(v3, 8, 64);
        if (lx == 0) {
            lred[w][quad * 4 + 0] = v0;
            lred[w][quad * 4 + 1] = v1;
            lred[w][quad * 4 + 2] = v2;
            lred[w][quad * 4 + 3] = v3;
        }
    }
    __syncthreads();
#pragma unroll
    for (int reg = 0; reg < 4; ++reg) {
        const int q = quad * 4 + reg;
        float lsum = 0.f;
#pragma unroll
        for (int ww = 0; ww < 8; ++ww) lsum += lred[ww][q];
        out[((size_t)(tb + qt) * 16 + q) * 128 + w * 16 + lx] = O[reg] / lsum;
    }
}

extern "C" void kernel_launch(void* const* d_in, const int* in_sizes, int n_in,
                              void* d_out, int out_size, void* d_ws, size_t ws_size,
                              hipStream_t stream) {
    const float4* X  = (const float4*)d_in[0];
    const float*  WQ = (const float*)d_in[1];
    const float*  WK = (const float*)d_in[2];
    const float*  WV = (const float*)d_in[3];

    f16* Wf = (f16*)d_ws;                     // 1024 frags  1 MB
    f16* Vf = Wf + (size_t)1024 * 512;        //  512 frags  0.5 MB
    f16* Qf = Vf + (size_t)512 * 512;         // 2048 frags  2 MB
    f16* Kf = Qf + (size_t)2048 * 512;        // 2048 frags  2 MB

    cvt_w_kernel<<<dim3(16, 8, 3), 256, 0, stream>>>(WQ, WK, WV, Wf, Vf);
    proj_kernel<<<256, 1024, 0, stream>>>(X, Wf, Qf, Kf);
    attn_kernel<<<512, 512, 0, stream>>>(Qf, Kf, Vf, (float*)d_out);
}

// Round 11
// 125.774 us; speedup vs baseline: 1.0598x; 1.0474x over previous
//
#include <hip/hip_runtime.h>
#include <stdint.h>

#define B 4
#define S 2048
#define E 2048
#define H 128

typedef _Float16 f16;
typedef _Float16 half4 __attribute__((ext_vector_type(4)));
typedef _Float16 half8 __attribute__((ext_vector_type(8)));
typedef float f32x4 __attribute__((ext_vector_type(4)));

// MFMA 16x16x32 f16 (m89/m91):
//   A-frag: lane(quad,lx) holds A[m=lx][k=quad*8+j]
//   B-frag: lane(quad,lx) holds B[k=quad*8+j][n=lx]
//   C/D  : lane(quad,lx) holds D[row=quad*4+reg][col=lx]
// FRAG-LINEAR GLOBAL: frag f = 512 f16 at dst[f*512 + lane*8 .. +8].

// Raw barrier: lgkm-only wait + s_barrier (no vmcnt drain).
#define BAR() do { asm volatile("s_waitcnt lgkmcnt(0)" ::: "memory"); \
    __builtin_amdgcn_s_barrier(); \
    asm volatile("" ::: "memory"); } while (0)

// ---------------------------------------------------------------------------
// Kernel 0: W matrices fp32 [128][2048] -> frag-linear f16. (original)
// ---------------------------------------------------------------------------
__global__ __launch_bounds__(256) void cvt_w_kernel(
    const float* __restrict__ WQ, const float* __restrict__ WK,
    const float* __restrict__ WV,
    f16* __restrict__ Wf, f16* __restrict__ Vf)
{
    __shared__ __align__(16) f16 LT[4 * 512];
    const int t   = threadIdx.x;
    const int cc  = blockIdx.x;
    const int rt  = blockIdx.y;
    const int mat = blockIdx.z;
    const float* src = (mat == 0) ? WQ : (mat == 1) ? WK : WV;

#pragma unroll
    for (int i = 0; i < 2; ++i) {
        const int idx = i * 256 + t;
        const int row = idx >> 5;
        const int c4  = idx & 31;
        float4 v = ((const float4*)src)[(size_t)(rt * 16 + row) * (E / 4) + cc * 32 + c4];
        const int e0   = c4 * 4;
        const int kcl  = e0 >> 5;
        const int quad = (e0 >> 3) & 3;
        const int j    = e0 & 7;
        half4 hv;
        hv[0] = (f16)v.x; hv[1] = (f16)v.y; hv[2] = (f16)v.z; hv[3] = (f16)v.w;
        *(half4*)&LT[(kcl * 64 + quad * 16 + row) * 8 + j] = hv;
    }
    __syncthreads();

    const half8 val = *(const half8*)&LT[t * 8];
    const int kcg = cc * 4 + (t >> 6);
    const int ln  = t & 63;
    if (mat == 2) *(half8*)&Vf[((size_t)kcg * 8  + rt)           * 512 + ln * 8] = val;
    else          *(half8*)&Wf[((size_t)kcg * 16 + rt + mat * 8) * 512 + ln * 8] = val;
}

// ---------------------------------------------------------------------------
// Kernel 1 (v2, best-known): Q,K projection. 256 blocks x 1024 thr, 32 rows,
// full-K X staged in 128 KB LDS (1 block/CU), coalesced staging + bank
// swizzle, barrier-free 64-iter K-loop, per-block kc rotation.
// Structural note (session ledger): pipelined variants (R3), 32x32 MFMA
// (R8), and 16-row/8-wave occupancy (R9) all measured equal or worse; the
// 128 KB full-K stage + barrier-free loop is the measured optimum.
// ---------------------------------------------------------------------------
__global__ __launch_bounds__(1024, 4) void proj_kernel(
    const float4* __restrict__ X,      // [B*S][E/4] fp32
    const f16* __restrict__ Wf,
    f16* __restrict__ Qf, f16* __restrict__ Kf)
{
    __shared__ __align__(16) f16 XA[8192 * 8];   // 128 KB; slot = 16B unit
    const int t    = threadIdx.x;
    const int w    = t >> 6;
    const int lane = t & 63;
    const int quad = lane >> 4;
    const int lx   = lane & 15;
    const int r0   = blockIdx.x * 32;

    float4 xv[16];
#pragma unroll
    for (int i = 0; i < 8; ++i) {
        const int p   = i * 1024 + t;
        const int row = p >> 8;
        const int c42 = p & 255;
        const float4* xp = &X[(size_t)(r0 + row) * (E / 4) + c42 * 2];
        xv[i * 2]     = xp[0];
        xv[i * 2 + 1] = xp[1];
    }
#pragma unroll
    for (int i = 0; i < 8; ++i) {
        const int p   = i * 1024 + t;
        const int row = p >> 8;
        const int c42 = p & 255;
        const int kc  = c42 >> 2;
        const int qs  = c42 & 3;
        const int rt  = row >> 4;
        const int m   = row & 15;
        const int mp  = m ^ ((qs << 1) | (kc & 1));      // bank swizzle
        half8 hv;
        hv[0] = (f16)xv[i * 2].x;     hv[1] = (f16)xv[i * 2].y;
        hv[2] = (f16)xv[i * 2].z;     hv[3] = (f16)xv[i * 2].w;
        hv[4] = (f16)xv[i * 2 + 1].x; hv[5] = (f16)xv[i * 2 + 1].y;
        hv[6] = (f16)xv[i * 2 + 1].z; hv[7] = (f16)xv[i * 2 + 1].w;
        *(half8*)&XA[(size_t)(kc * 128 + rt * 64 + qs * 16 + mp) * 8] = hv;
    }
    __syncthreads();

    f32x4 C0 = f32x4{0.f, 0.f, 0.f, 0.f};
    f32x4 C1 = f32x4{0.f, 0.f, 0.f, 0.f};
    const f16* wbase = &Wf[(size_t)w * 512 + lane * 8];     // frag kc*16 + w
    const int rot = blockIdx.x & 63;
#pragma unroll 8
    for (int kk = 0; kk < 64; ++kk) {
        const int kc  = (kk + rot) & 63;
        const int lxs = lx ^ ((quad << 1) | (kc & 1));
        half8 b  = *(const half8*)&wbase[(size_t)kc * 16 * 512];          // L2
        half8 a0 = *(const half8*)&XA[(size_t)(kc * 128      + quad * 16 + lxs) * 8];
        half8 a1 = *(const half8*)&XA[(size_t)(kc * 128 + 64 + quad * 16 + lxs) * 8];
        C0 = __builtin_amdgcn_mfma_f32_16x16x32_f16(a0, b, C0, 0, 0, 0);
        C1 = __builtin_amdgcn_mfma_f32_16x16x32_f16(a1, b, C1, 0, 0, 0);
    }

    __syncthreads();                      // all XA reads done; alias as LT
    f16* LT = XA;                         // 16 frags = 16 KB
    {
        const int qt2 = (w & 1) * 2 + (lx >> 3);
        const int jt  = lx & 7;
        const int fl  = w >> 1;           // 0..7: (mat,hc)
#pragma unroll
        for (int reg = 0; reg < 4; ++reg) {
            LT[(size_t)((fl      * 64) + qt2 * 16 + quad * 4 + reg) * 8 + jt] = (f16)C0[reg];
            LT[(size_t)(((fl + 8) * 64) + qt2 * 16 + quad * 4 + reg) * 8 + jt] = (f16)C1[reg];
        }
    }
    __syncthreads();
    {
        const int f  = t >> 6;            // 0..15
        const int ln = t & 63;
        const half8 v = *(const half8*)&LT[(size_t)f * 512 + ln * 8];
        const int rt  = f >> 3;
        const int hc  = f & 3;
        const int mat = (f >> 2) & 1;
        f16* dst = mat ? Kf : Qf;
        *(half8*)&dst[((size_t)(blockIdx.x * 2 + rt) * 4 + hc) * 512 + ln * 8] = v;
    }
}

// ---------------------------------------------------------------------------
// Kernel 2 (v4 @ lb(512,4), best-known from R6): attention, R4 CU-balanced
// map. Ledger: lb(512,2) measured -4.6 us (R10); wave re-splits and XCD
// maps neutral (R5-R7). R9's "123us attn" row was a first-dispatch rocprof
// artifact, not steady state.
// ---------------------------------------------------------------------------
__global__ __launch_bounds__(512, 4) void attn_kernel(
    const f16* __restrict__ Qf, const f16* __restrict__ Kf,
    const f16* __restrict__ Vf,
    float* __restrict__ out)
{
    __shared__ __align__(16) f16 PL[2 * 4 * 512];   // 8 KB, parity-buffered
    __shared__ float lred[8][16];

    const int t    = threadIdx.x;
    const int w    = t >> 6;
    const int lane = t & 63;
    const int quad = lane >> 4;
    const int lx   = lane & 15;

    const int j    = blockIdx.x & 255;
    const int r    = blockIdx.x >> 8;
    const int u    = j & 127;
    const int q0t  = (u & 1) ? (127 - (u >> 1)) : (u >> 1);
    const int qt   = r ? (127 - q0t) : q0t;
    const int b    = (j >> 7) + (r << 1);
    const int q0   = qt * 16;
    const int tb   = b * 128;

    half8 qa0, qa1, qa2, qa3;
    {
        const f16* qp = &Qf[(((size_t)(tb + qt)) * 4) * 512 + lane * 8];
        qa0 = *(const half8*)&qp[0];    qa1 = *(const half8*)&qp[512];
        qa2 = *(const half8*)&qp[1024]; qa3 = *(const half8*)&qp[1536];
    }

    f32x4 O = f32x4{0.f, 0.f, 0.f, 0.f};
    float lp0 = 0.f, lp1 = 0.f, lp2 = 0.f, lp3 = 0.f;

    const int nch = (qt >> 3) + 1;

    half8 kbA0, kbA1, kbA2, kbA3, vbA0, vbA1, vbA2, vbA3;
    half8 kbB0, kbB1, kbB2, kbB3, vbB0, vbB1, vbB2, vbB3;

#define LOADKV(c, K0, K1, K2, K3, V0, V1, V2, V3)                              \
    {                                                                          \
        const f16* kp_ = &Kf[(((size_t)(tb + (c) * 8 + w)) * 4) * 512 + lane * 8]; \
        K0 = *(const half8*)&kp_[0];    K1 = *(const half8*)&kp_[512];         \
        K2 = *(const half8*)&kp_[1024]; K3 = *(const half8*)&kp_[1536];        \
        const f16* vp_ = &Vf[(((size_t)(c) * 4 * 8) + w) * 512 + lane * 8];    \
        V0 = *(const half8*)&vp_[0];     V1 = *(const half8*)&vp_[4096];       \
        V2 = *(const half8*)&vp_[8192];  V3 = *(const half8*)&vp_[12288];      \
    }

#define STEP(c, K0, K1, K2, K3, V0, V1, V2, V3, NK0, NK1, NK2, NK3, NV0, NV1, NV2, NV3) \
    {                                                                          \
        if ((c) + 1 < nch) LOADKV((c) + 1, NK0, NK1, NK2, NK3, NV0, NV1, NV2, NV3) \
        f32x4 Sc = f32x4{0.f, 0.f, 0.f, 0.f};                                  \
        __builtin_amdgcn_s_setprio(1);                                         \
        Sc = __builtin_amdgcn_mfma_f32_16x16x32_f16(qa0, K0, Sc, 0, 0, 0);     \
        Sc = __builtin_amdgcn_mfma_f32_16x16x32_f16(qa1, K1, Sc, 0, 0, 0);     \
        Sc = __builtin_amdgcn_mfma_f32_16x16x32_f16(qa2, K2, Sc, 0, 0, 0);     \
        Sc = __builtin_amdgcn_mfma_f32_16x16x32_f16(qa3, K3, Sc, 0, 0, 0);     \
        __builtin_amdgcn_s_setprio(0);                                         \
        const int sgc_ = (c) * 128 + w * 16 + lx;                              \
        const int qp2_ = (w & 1) * 2 + (lx >> 3);                              \
        f16* plw_ = &PL[((c) & 1) * 2048 + (w >> 1) * 512];                    \
        _Pragma("unroll")                                                      \
        for (int reg = 0; reg < 4; ++reg) {                                    \
            const int q_ = quad * 4 + reg;                                     \
            float p_ = (sgc_ <= q0 + q_)                                       \
                       ? __expf(Sc[reg] * 0.08838834764831845f - 10.0f)        \
                       : 0.f;                                                  \
            if (reg == 0) lp0 += p_; else if (reg == 1) lp1 += p_;             \
            else if (reg == 2) lp2 += p_; else lp3 += p_;                      \
            plw_[(qp2_ * 16 + q_) * 8 + (lx & 7)] = (f16)p_;                   \
        }                                                                      \
        BAR();                                                                 \
        const f16* plr_ = &PL[((c) & 1) * 2048];                               \
        const half8 pa0_ = *(const half8*)&plr_[lane * 8];                     \
        const half8 pa1_ = *(const half8*)&plr_[512 + lane * 8];               \
        const half8 pa2_ = *(const half8*)&plr_[1024 + lane * 8];              \
        const half8 pa3_ = *(const half8*)&plr_[1536 + lane * 8];              \
        __builtin_amdgcn_s_setprio(1);                                         \
        O = __builtin_amdgcn_mfma_f32_16x16x32_f16(pa0_, V0, O, 0, 0, 0);      \
        O = __builtin_amdgcn_mfma_f32_16x16x32_f16(pa1_, V1, O, 0, 0, 0);      \
        O = __builtin_amdgcn_mfma_f32_16x16x32_f16(pa2_, V2, O, 0, 0, 0);      \
        O = __builtin_amdgcn_mfma_f32_16x16x32_f16(pa3_, V3, O, 0, 0, 0);      \
        __builtin_amdgcn_s_setprio(0);                                         \
    }

    LOADKV(0, kbA0, kbA1, kbA2, kbA3, vbA0, vbA1, vbA2, vbA3)
    int c = 0;
    while (true) {
        STEP(c, kbA0, kbA1, kbA2, kbA3, vbA0, vbA1, vbA2, vbA3,
                kbB0, kbB1, kbB2, kbB3, vbB0, vbB1, vbB2, vbB3)
        ++c; if (c >= nch) break;
        STEP(c, kbB0, kbB1, kbB2, kbB3, vbB0, vbB1, vbB2, vbB3,
                kbA0, kbA1, kbA2, kbA3, vbA0, vbA1, vbA2, vbA3)
        ++c; if (c >= nch) break;
    }
#undef STEP
#undef LOADKV

    {
        float v0 = lp0, v1 = lp1, v2 = lp2, v3 = lp3;
        v0 += __shfl_xor(v0, 1, 64); v0 += __shfl_xor(v0, 2, 64);
        v0 += __shfl_xor(v0, 4, 64); v0 += __shfl_xor(v0, 8, 64);
        v1 += __shfl_xor(v1, 1, 64); v1 += __shfl_xor(v1, 2, 64);
        v1 += __shfl_xor(v1, 4, 64); v1 += __shfl_xor(v1, 8, 64);
        v2 += __shfl_xor(v2, 1, 64); v2 += __shfl_xor(v2, 2, 64);
        v2 += __shfl_xor(v2, 4, 64); v2 += __shfl_xor(v2, 8, 64);
        v3 += __shfl_xor(v3, 1, 64); v3 += __shfl_xor(v3, 2, 64);
        v3 += __shfl_xor(v3, 4, 64); v3 += __shfl_xor(v3, 8, 64);
        if (lx == 0) {
            lred[w][quad * 4 + 0] = v0;
            lred[w][quad * 4 + 1] = v1;
            lred[w][quad * 4 + 2] = v2;
            lred[w][quad * 4 + 3] = v3;
        }
    }
    __syncthreads();
#pragma unroll
    for (int reg = 0; reg < 4; ++reg) {
        const int q = quad * 4 + reg;
        float lsum = 0.f;
#pragma unroll
        for (int ww = 0; ww < 8; ++ww) lsum += lred[ww][q];
        out[((size_t)(tb + qt) * 16 + q) * 128 + w * 16 + lx] = O[reg] / lsum;
    }
}

extern "C" void kernel_launch(void* const* d_in, const int* in_sizes, int n_in,
                              void* d_out, int out_size, void* d_ws, size_t ws_size,
                              hipStream_t stream) {
    const float4* X  = (const float4*)d_in[0];
    const float*  WQ = (const float*)d_in[1];
    const float*  WK = (const float*)d_in[2];
    const float*  WV = (const float*)d_in[3];

    f16* Wf = (f16*)d_ws;                     // 1024 frags  1 MB
    f16* Vf = Wf + (size_t)1024 * 512;        //  512 frags  0.5 MB
    f16* Qf = Vf + (size_t)512 * 512;         // 2048 frags  2 MB
    f16* Kf = Qf + (size_t)2048 * 512;        // 2048 frags  2 MB

    cvt_w_kernel<<<dim3(16, 8, 3), 256, 0, stream>>>(WQ, WK, WV, Wf, Vf);
    proj_kernel<<<256, 1024, 0, stream>>>(X, Wf, Qf, Kf);
    attn_kernel<<<512, 512, 0, stream>>>(Qf, Kf, Vf, (float*)d_out);
}